// Round 9
// baseline (1370.844 us; speedup 1.0000x reference)
//
#include <hip/hip_runtime.h>
#include <hip/hip_cooperative_groups.h>

namespace cg = cooperative_groups;

// LightGCN propagation on MI355X — single cooperative mega-kernel.
// N = 150000 nodes, D = 64, E = 1.2M edges, 4 layers.
// z = dinv .* emb (fp16), separable norm; binned CSR build; all phases in
// one kernel with grid.sync() (kills ~80us of launch gaps measured r8).
// Final layer computes z4 in-register and writes
//   acc = emb0/25 + (z1+z2+z3+z4)*sqrtdeg/25   (pure write, no init pass).
// Fallback to the proven round-8 10-kernel path if coop launch is rejected.

#define DIMH 64
#define BLK 256
#define BSHIFT 9                    // 512 nodes per bucket
#define BNODES 512
#define EB 8192                     // edges per scatter chunk

typedef float    f4  __attribute__((ext_vector_type(4)));
typedef _Float16 h4  __attribute__((ext_vector_type(4)));

__device__ inline f4 cvt(h4 v) { return __builtin_convertvector(v, f4); }

// gather one layer: 16 lanes per dst node, lane owns 4 dims (8B fp16).
__device__ void gather_phase(const _Float16* __restrict__ cur,
                             _Float16* __restrict__ nxt,
                             const float* __restrict__ dinv,
                             const int* __restrict__ rowptr,
                             const int* __restrict__ edges,
                             long N, long gid, long gthreads) {
    for (long g = gid; g < N * 16; g += gthreads) {
        long node = g >> 4;
        int q = (int)(g & 15);
        int beg = rowptr[node];
        int end = rowptr[node + 1];
        f4 s = {0.f, 0.f, 0.f, 0.f};
        f4 t2 = {0.f, 0.f, 0.f, 0.f};
        for (int base = beg; base < end; base += 16) {
            int me = base + q;
            int psrc = (me < end) ? edges[me] : 0;
            int n = end - base;
            if (n > 16) n = 16;
            int j = 0;
            for (; j + 4 <= n; j += 4) {
                int a0 = __shfl(psrc, j + 0, 16);
                int a1 = __shfl(psrc, j + 1, 16);
                int a2 = __shfl(psrc, j + 2, 16);
                int a3 = __shfl(psrc, j + 3, 16);
                h4 v0 = ((const h4*)(cur + (long)a0 * DIMH))[q];
                h4 v1 = ((const h4*)(cur + (long)a1 * DIMH))[q];
                h4 v2 = ((const h4*)(cur + (long)a2 * DIMH))[q];
                h4 v3 = ((const h4*)(cur + (long)a3 * DIMH))[q];
                s  += cvt(v0); t2 += cvt(v1); s += cvt(v2); t2 += cvt(v3);
            }
            for (; j < n; ++j) {
                int a = __shfl(psrc, j, 16);
                s += cvt(((const h4*)(cur + (long)a * DIMH))[q]);
            }
        }
        s += t2;
        float d = dinv[node];
        ((h4*)(nxt + node * DIMH))[q] = __builtin_convertvector(s * (d * d), h4);
    }
}

__global__ void __launch_bounds__(BLK, 8)
k_mega(const float* __restrict__ uemb, const float* __restrict__ iemb,
       const int* __restrict__ row, const int* __restrict__ col,
       int* __restrict__ bucketCnt, int* __restrict__ bucketPtr,
       int* __restrict__ bucketCur, int2* __restrict__ staging,
       int* __restrict__ edges, int* __restrict__ rowptr,
       float* __restrict__ dinv,
       _Float16* __restrict__ z0, _Float16* __restrict__ z1,
       _Float16* __restrict__ z2, _Float16* __restrict__ z3,
       float* __restrict__ acc,
       long uElems, long total, long N, long E, int NB) {
    cg::grid_group grid = cg::this_grid();
    __shared__ int smem[1792];  // 7 KB, aliased per phase
    const int tid = threadIdx.x;
    const int bid = blockIdx.x;
    const long gthreads = (long)gridDim.x * BLK;
    const long gid = (long)bid * BLK + tid;

    // ---- P0: z0 = fp16(concat(uemb,iemb)); zero bucketCnt ----
    for (long t = gid; t < (total >> 2); t += gthreads) {
        long base = t * 4;
        f4 v = (base < uElems) ? *(const f4*)(uemb + base)
                               : *(const f4*)(iemb + (base - uElems));
        *(h4*)(z0 + base) = __builtin_convertvector(v, h4);
    }
    if (gid < 1024) bucketCnt[gid] = 0;
    grid.sync();

    // ---- P1: bucket histogram over dst ----
    {
        int* h = smem;
        for (int i = tid; i < BNODES; i += BLK) h[i] = 0;
        __syncthreads();
        for (long e = gid; e < E; e += gthreads)
            atomicAdd(&h[col[e] >> BSHIFT], 1);
        __syncthreads();
        for (int i = tid; i < BNODES; i += BLK)
            if (h[i]) atomicAdd(&bucketCnt[i], h[i]);
    }
    grid.sync();

    // ---- P2: exclusive scan of bucketCnt (block 0 only) ----
    if (bid == 0) {
        int* lds = smem;
        int t = tid;
        int v0 = (2 * t < NB) ? bucketCnt[2 * t] : 0;
        int v1 = (2 * t + 1 < NB) ? bucketCnt[2 * t + 1] : 0;
        lds[t] = v0 + v1;
        __syncthreads();
        for (int off = 1; off < BLK; off <<= 1) {
            int mine = lds[t];
            int add = (t >= off) ? lds[t - off] : 0;
            __syncthreads();
            lds[t] = mine + add;
            __syncthreads();
        }
        int excl = (t > 0) ? lds[t - 1] : 0;
        if (2 * t < NB)     { bucketPtr[2 * t] = excl;          bucketCur[2 * t] = excl; }
        if (2 * t + 1 < NB) { bucketPtr[2 * t + 1] = excl + v0; bucketCur[2 * t + 1] = excl + v0; }
        if (t == 0) { bucketPtr[NB] = (int)E; rowptr[N] = (int)E; }
    }
    grid.sync();

    // ---- P3: scatter (src,dst) into bucket-grouped staging ----
    {
        int* h  = smem;
        int* gb = smem + 512;
        int* lc = smem + 1024;
        const int nchunks = (int)((E + EB - 1) / EB);
        for (int c = bid; c < nchunks; c += gridDim.x) {
            const long e0 = (long)c * EB;
            const int n = (int)((E - e0 < EB) ? (E - e0) : EB);
            for (int i = tid; i < BNODES; i += BLK) h[i] = 0;
            __syncthreads();
            for (int i = tid; i < n; i += BLK)
                atomicAdd(&h[col[e0 + i] >> BSHIFT], 1);
            __syncthreads();
            for (int b = tid; b < BNODES; b += BLK) {
                int cc = h[b];
                gb[b] = cc ? atomicAdd(&bucketCur[b], cc) : 0;
                lc[b] = 0;
            }
            __syncthreads();
            for (int i = tid; i < n; i += BLK) {
                int cc = col[e0 + i];
                int rr = row[e0 + i];
                int b = cc >> BSHIFT;
                int pos = gb[b] + atomicAdd(&lc[b], 1);
                staging[pos] = make_int2(rr, cc);
            }
            __syncthreads();
        }
    }
    grid.sync();

    // ---- P4: per-bucket count/scan/place + scale z0 by dinv ----
    for (int b = bid; b < NB; b += gridDim.x) {
        int*   cnt = smem;
        int*   cur = smem + 512;
        int*   lds = smem + 1024;           // 256
        float* dnv = (float*)(smem + 1280); // 512
        const long lo = (long)b << BSHIFT;
        const int R = (int)(((N - lo) < BNODES) ? (N - lo) : BNODES);
        const int beg = bucketPtr[b];
        const int end = bucketPtr[b + 1];
        const int t = tid;

        for (int i = t; i < BNODES; i += BLK) cnt[i] = 0;
        __syncthreads();
        for (int e = beg + t; e < end; e += BLK)
            atomicAdd(&cnt[staging[e].y - (int)lo], 1);
        __syncthreads();

        int v0 = cnt[2 * t];
        int v1 = cnt[2 * t + 1];
        lds[t] = v0 + v1;
        __syncthreads();
        for (int off = 1; off < BLK; off <<= 1) {
            int mine = lds[t];
            int add = (t >= off) ? lds[t - off] : 0;
            __syncthreads();
            lds[t] = mine + add;
            __syncthreads();
        }
        int excl = (t > 0) ? lds[t - 1] : 0;
        int e0 = beg + excl;
        int e1 = e0 + v0;
        cur[2 * t] = e0;
        cur[2 * t + 1] = e1;
        dnv[2 * t] = (v0 > 0) ? rsqrtf((float)v0) : 0.0f;
        dnv[2 * t + 1] = (v1 > 0) ? rsqrtf((float)v1) : 0.0f;
        if (2 * t < R)     { rowptr[lo + 2 * t] = e0;     dinv[lo + 2 * t] = dnv[2 * t]; }
        if (2 * t + 1 < R) { rowptr[lo + 2 * t + 1] = e1; dinv[lo + 2 * t + 1] = dnv[2 * t + 1]; }
        __syncthreads();

        for (int e = beg + t; e < end; e += BLK) {
            int2 p = staging[e];
            int pos = atomicAdd(&cur[p.y - (int)lo], 1);
            edges[pos] = p.x;
        }

        for (int i = t; i < R * 16; i += BLK) {
            int nloc = i >> 4;
            int q = i & 15;
            float d = dnv[nloc];
            h4* p = (h4*)(z0 + (lo + nloc) * DIMH) + q;
            *p = __builtin_convertvector(cvt(*p) * d, h4);
        }
        __syncthreads();
    }
    grid.sync();

    // ---- P5-P7: gather layers 1..3 ----
    gather_phase(z0, z1, dinv, rowptr, edges, N, gid, gthreads);
    grid.sync();
    gather_phase(z1, z2, dinv, rowptr, edges, N, gid, gthreads);
    grid.sync();
    gather_phase(z2, z3, dinv, rowptr, edges, N, gid, gthreads);
    grid.sync();

    // ---- P8: layer 4 in-register + final accumulate (pure write) ----
    for (long g = gid; g < N * 16; g += gthreads) {
        long node = g >> 4;
        int q = (int)(g & 15);
        int beg = rowptr[node];
        int end = rowptr[node + 1];
        f4 s = {0.f, 0.f, 0.f, 0.f};
        f4 t2 = {0.f, 0.f, 0.f, 0.f};
        for (int base = beg; base < end; base += 16) {
            int me = base + q;
            int psrc = (me < end) ? edges[me] : 0;
            int n = end - base;
            if (n > 16) n = 16;
            int j = 0;
            for (; j + 4 <= n; j += 4) {
                int a0 = __shfl(psrc, j + 0, 16);
                int a1 = __shfl(psrc, j + 1, 16);
                int a2 = __shfl(psrc, j + 2, 16);
                int a3 = __shfl(psrc, j + 3, 16);
                s  += cvt(((const h4*)(z3 + (long)a0 * DIMH))[q]);
                t2 += cvt(((const h4*)(z3 + (long)a1 * DIMH))[q]);
                s  += cvt(((const h4*)(z3 + (long)a2 * DIMH))[q]);
                t2 += cvt(((const h4*)(z3 + (long)a3 * DIMH))[q]);
            }
            for (; j < n; ++j) {
                int a = __shfl(psrc, j, 16);
                s += cvt(((const h4*)(z3 + (long)a * DIMH))[q]);
            }
        }
        s += t2;
        float d = dinv[node];
        long off = node * DIMH + q * 4;
        f4 z4 = s * (d * d);
        f4 zs = cvt(*(const h4*)(z1 + off)) + cvt(*(const h4*)(z2 + off))
              + cvt(*(const h4*)(z3 + off)) + z4;
        float f = (d > 0.f) ? (1.0f / d) * (1.0f / 25.0f) : 0.f;
        f4 e0 = (off < uElems) ? *(const f4*)(uemb + off)
                               : *(const f4*)(iemb + (off - uElems));
        *(f4*)(acc + off) = e0 * (1.0f / 25.0f) + zs * f;
    }
}

// ===========================================================================
// Fallback path — proven round-8 kernels (used if coop launch is rejected).
// ===========================================================================
__global__ void k_init(const float* __restrict__ uemb, const float* __restrict__ iemb,
                       _Float16* __restrict__ embA, float* __restrict__ acc,
                       int* __restrict__ bucketCnt, long uElems, long totalElems) {
    long t = (long)blockIdx.x * BLK + threadIdx.x;
    if (t < 1024) bucketCnt[t] = 0;
    long base = t * 4;
    if (base >= totalElems) return;
    f4 v = (base < uElems) ? *(const f4*)(uemb + base)
                           : *(const f4*)(iemb + (base - uElems));
    *(h4*)(embA + base) = __builtin_convertvector(v, h4);
    *(f4*)(acc + base) = v * (1.0f / 25.0f);
}

__global__ void k_binhist(const int* __restrict__ col, int* __restrict__ bucketCnt,
                          long E) {
    __shared__ int h[BNODES];
    for (int i = threadIdx.x; i < BNODES; i += BLK) h[i] = 0;
    __syncthreads();
    const long stride = (long)gridDim.x * BLK;
    for (long e = (long)blockIdx.x * BLK + threadIdx.x; e < E; e += stride)
        atomicAdd(&h[col[e] >> BSHIFT], 1);
    __syncthreads();
    for (int i = threadIdx.x; i < BNODES; i += BLK)
        if (h[i]) atomicAdd(&bucketCnt[i], h[i]);
}

__global__ void k_binscan(const int* __restrict__ bucketCnt, int* __restrict__ bucketPtr,
                          int* __restrict__ bucketCur, int NB, int E,
                          int* __restrict__ rowptrN) {
    __shared__ int lds[BLK];
    int t = threadIdx.x;
    int v0 = (2 * t < NB) ? bucketCnt[2 * t] : 0;
    int v1 = (2 * t + 1 < NB) ? bucketCnt[2 * t + 1] : 0;
    lds[t] = v0 + v1;
    __syncthreads();
    for (int off = 1; off < BLK; off <<= 1) {
        int mine = lds[t];
        int add = (t >= off) ? lds[t - off] : 0;
        __syncthreads();
        lds[t] = mine + add;
        __syncthreads();
    }
    int excl = (t > 0) ? lds[t - 1] : 0;
    if (2 * t < NB)     { bucketPtr[2 * t] = excl;          bucketCur[2 * t] = excl; }
    if (2 * t + 1 < NB) { bucketPtr[2 * t + 1] = excl + v0; bucketCur[2 * t + 1] = excl + v0; }
    if (t == 0) { bucketPtr[NB] = E; *rowptrN = E; }
}

__global__ void k_binscatter(const int* __restrict__ row, const int* __restrict__ col,
                             int* __restrict__ bucketCur, int2* __restrict__ staging,
                             long E) {
    __shared__ int h[BNODES];
    __shared__ int gb[BNODES];
    __shared__ int lc[BNODES];
    const long e0 = (long)blockIdx.x * EB;
    const int n = (int)((E - e0 < EB) ? (E - e0) : EB);
    for (int i = threadIdx.x; i < BNODES; i += BLK) h[i] = 0;
    __syncthreads();
    for (int i = threadIdx.x; i < n; i += BLK)
        atomicAdd(&h[col[e0 + i] >> BSHIFT], 1);
    __syncthreads();
    for (int b = threadIdx.x; b < BNODES; b += BLK) {
        int c = h[b];
        gb[b] = c ? atomicAdd(&bucketCur[b], c) : 0;
        lc[b] = 0;
    }
    __syncthreads();
    for (int i = threadIdx.x; i < n; i += BLK) {
        int c = col[e0 + i];
        int r = row[e0 + i];
        int b = c >> BSHIFT;
        int pos = gb[b] + atomicAdd(&lc[b], 1);
        staging[pos] = make_int2(r, c);
    }
}

__global__ void k_bucket(const int2* __restrict__ staging, const int* __restrict__ bucketPtr,
                         int* __restrict__ edges, int* __restrict__ rowptr,
                         float* __restrict__ dinv, _Float16* __restrict__ embA, long N) {
    __shared__ int cnt[BNODES];
    __shared__ int cur[BNODES];
    __shared__ float dnv[BNODES];
    __shared__ int lds[BLK];
    const int b = blockIdx.x;
    const long lo = (long)b << BSHIFT;
    const int R = (int)(((N - lo) < BNODES) ? (N - lo) : BNODES);
    const int beg = bucketPtr[b];
    const int end = bucketPtr[b + 1];
    const int t = threadIdx.x;

    for (int i = t; i < BNODES; i += BLK) cnt[i] = 0;
    __syncthreads();
    for (int e = beg + t; e < end; e += BLK)
        atomicAdd(&cnt[staging[e].y - (int)lo], 1);
    __syncthreads();

    int v0 = cnt[2 * t];
    int v1 = cnt[2 * t + 1];
    lds[t] = v0 + v1;
    __syncthreads();
    for (int off = 1; off < BLK; off <<= 1) {
        int mine = lds[t];
        int add = (t >= off) ? lds[t - off] : 0;
        __syncthreads();
        lds[t] = mine + add;
        __syncthreads();
    }
    int excl = (t > 0) ? lds[t - 1] : 0;
    int e0 = beg + excl;
    int e1 = e0 + v0;
    cur[2 * t] = e0;
    cur[2 * t + 1] = e1;
    dnv[2 * t] = (v0 > 0) ? rsqrtf((float)v0) : 0.0f;
    dnv[2 * t + 1] = (v1 > 0) ? rsqrtf((float)v1) : 0.0f;
    if (2 * t < R)     { rowptr[lo + 2 * t] = e0;     dinv[lo + 2 * t] = dnv[2 * t]; }
    if (2 * t + 1 < R) { rowptr[lo + 2 * t + 1] = e1; dinv[lo + 2 * t + 1] = dnv[2 * t + 1]; }
    __syncthreads();

    for (int e = beg + t; e < end; e += BLK) {
        int2 p = staging[e];
        int pos = atomicAdd(&cur[p.y - (int)lo], 1);
        edges[pos] = p.x;
    }
    for (int i = t; i < R * 16; i += BLK) {
        int nloc = i >> 4;
        int q = i & 15;
        float d = dnv[nloc];
        h4* p = (h4*)(embA + (lo + nloc) * DIMH) + q;
        *p = __builtin_convertvector(cvt(*p) * d, h4);
    }
}

__global__ void __launch_bounds__(BLK)
k_gather(const _Float16* __restrict__ cur, _Float16* __restrict__ nxt,
         const float* __restrict__ dinv,
         const int* __restrict__ rowptr, const int* __restrict__ edges, long N) {
    long g = (long)blockIdx.x * BLK + threadIdx.x;
    if (g >= N * 16) return;
    gather_phase(cur, nxt, dinv, rowptr, edges, N, g, (long)gridDim.x * BLK);
}

__global__ void __launch_bounds__(BLK)
k_final(const _Float16* __restrict__ z1, const _Float16* __restrict__ z2,
        const _Float16* __restrict__ z3, const _Float16* __restrict__ z4,
        const float* __restrict__ dinv, float* __restrict__ acc, long N) {
    long g = (long)blockIdx.x * BLK + threadIdx.x;
    if (g >= N * 16) return;
    long node = g >> 4;
    int q = (int)(g & 15);
    float d = dinv[node];
    float f = (d > 0.f) ? (1.0f / d) * (1.0f / 25.0f) : 0.f;
    long off = node * DIMH + q * 4;
    f4 zs = cvt(*(const h4*)(z1 + off)) + cvt(*(const h4*)(z2 + off))
          + cvt(*(const h4*)(z3 + off)) + cvt(*(const h4*)(z4 + off));
    f4 a = *(const f4*)(acc + off);
    *(f4*)(acc + off) = a + zs * f;
}

// ---------------------------------------------------------------------------
extern "C" void kernel_launch(void* const* d_in, const int* in_sizes, int n_in,
                              void* d_out, int out_size, void* d_ws, size_t ws_size,
                              hipStream_t stream) {
    const float* uemb = (const float*)d_in[0];
    const float* iemb = (const float*)d_in[1];
    const int*   edge = (const int*)d_in[2];

    const long uElems = in_sizes[0];          // 100000*64
    const long iElems = in_sizes[1];          // 50000*64
    const long E      = in_sizes[2] / 2;      // 1200000
    const long total  = uElems + iElems;      // N*64
    const long N      = total / DIMH;         // 150000

    const int* row = edge;      // edge_index[0] = src
    const int* col = edge + E;  // edge_index[1] = dst

    float* acc = (float*)d_out;
    const int NB = (int)((N + BNODES - 1) >> BSHIFT);   // 293 buckets

    // workspace layout (all bases 256B-aligned)
    const long Npad = (N + 63) & ~63L;
    const long Epad = (E + 63) & ~63L;
    int*      rowptr    = (int*)d_ws;                 // N+1 ints
    float*    dinv      = (float*)(rowptr + Npad + 64);
    int*      edges     = (int*)(dinv + Npad);        // E src indices
    int*      bucketCnt = edges + Epad;               // 1024
    int*      bucketPtr = bucketCnt + 1024;           // 1024 (NB+1 used)
    int*      bucketCur = bucketPtr + 1024;           // 1024
    _Float16* z0        = (_Float16*)(bucketCur + 1024); // N*64 fp16
    _Float16* z1        = z0 + total;
    _Float16* z2        = z1 + total;
    _Float16* z3        = z2 + total;
    _Float16* z4        = z3 + total;                 // fallback only
    int2*     staging   = (int2*)z1;   // consumed (P4/bucket) before z1 written

    // ---- cooperative path ----
    int maxB = 0;
    hipError_t qerr = hipOccupancyMaxActiveBlocksPerMultiprocessor(&maxB, k_mega, BLK, 0);
    hipError_t lerr = hipErrorUnknown;
    if (qerr == hipSuccess && maxB > 0) {
        int grid = maxB * 256;            // 256 CUs on gfx950
        if (grid > 2048) grid = 2048;
        long uE = uElems, tot = total, n_ = N, e_ = E;
        int nb_ = NB;
        void* args[] = {(void*)&uemb, (void*)&iemb, (void*)&row, (void*)&col,
                        (void*)&bucketCnt, (void*)&bucketPtr, (void*)&bucketCur,
                        (void*)&staging, (void*)&edges, (void*)&rowptr,
                        (void*)&dinv, (void*)&z0, (void*)&z1, (void*)&z2,
                        (void*)&z3, (void*)&acc,
                        (void*)&uE, (void*)&tot, (void*)&n_, (void*)&e_,
                        (void*)&nb_};
        lerr = hipLaunchCooperativeKernel(k_mega, dim3(grid), dim3(BLK),
                                          args, 0, stream);
    }
    if (lerr == hipSuccess) return;

    // ---- fallback: proven round-8 sequence ----
    const long total4 = total / 4;
    const int gInit = (int)((total4 + BLK - 1) / BLK);
    k_init<<<gInit, BLK, 0, stream>>>(uemb, iemb, z0, acc, bucketCnt, uElems, total);
    k_binhist<<<512, BLK, 0, stream>>>(col, bucketCnt, E);
    k_binscan<<<1, BLK, 0, stream>>>(bucketCnt, bucketPtr, bucketCur, NB, (int)E,
                                     rowptr + N);
    k_binscatter<<<(int)((E + EB - 1) / EB), BLK, 0, stream>>>(row, col, bucketCur,
                                                               staging, E);
    k_bucket<<<NB, BLK, 0, stream>>>(staging, bucketPtr, edges, rowptr, dinv, z0, N);

    const int gGather = (int)((N * 16 + BLK - 1) / BLK);
    _Float16* zs[5] = {z0, z1, z2, z3, z4};
    for (int l = 0; l < 4; ++l)
        k_gather<<<gGather, BLK, 0, stream>>>(zs[l], zs[l + 1], dinv, rowptr, edges, N);
    k_final<<<gGather, BLK, 0, stream>>>(z1, z2, z3, z4, dinv, acc, N);
}

// Round 10
// 284.287 us; speedup vs baseline: 4.8220x; 4.8220x over previous
//
#include <hip/hip_runtime.h>

// LightGCN propagation on MI355X — CSR-gather, separable-norm, binned CSR
// build, fp16 state, deferred+fused final accumulation.
// N = 150000 nodes, D = 64, E = 1.2M edges, 4 layers.
// z = dinv .* emb (fp16). Layers 1-3 write z_l only; layer 4 is fused with
// the final accumulate (algebra verified in round 9's mega-kernel):
//   acc = emb0/25 + (z1+z2+z3+z4_inreg) * sqrtdeg/25   (pure write).
// LESSON (r9): cooperative grid.sync() on MI355X costs milliseconds
// (XCD-noncoherence fences + cache flush) — separate launches only.
// LESSON (r4): no nontemporal stores on random scatters.

#define DIMH 64
#define BLK 256
#define BSHIFT 9                    // 512 nodes per bucket
#define BNODES 512
#define EB 8192                     // edges per binscatter block

typedef float    f4  __attribute__((ext_vector_type(4)));
typedef _Float16 h4  __attribute__((ext_vector_type(4)));

__device__ inline f4 cvt(h4 v) { return __builtin_convertvector(v, f4); }

// ---------------------------------------------------------------------------
// init: z0(h16) = concat(user, item); bucketCnt = 0 (fused). No acc pass —
// acc is produced write-only by k_g4final.
__global__ void k_init(const float* __restrict__ uemb, const float* __restrict__ iemb,
                       _Float16* __restrict__ z0, int* __restrict__ bucketCnt,
                       long uElems, long totalElems) {
    long t = (long)blockIdx.x * BLK + threadIdx.x;
    if (t < 1024) bucketCnt[t] = 0;
    long base = t * 4;
    if (base >= totalElems) return;
    f4 v = (base < uElems) ? *(const f4*)(uemb + base)
                           : *(const f4*)(iemb + (base - uElems));
    *(h4*)(z0 + base) = __builtin_convertvector(v, h4);
}

// bucket histogram over dst (LDS pre-aggregation, few global atomics).
__global__ void k_binhist(const int* __restrict__ col, int* __restrict__ bucketCnt,
                          long E) {
    __shared__ int h[BNODES];
    for (int i = threadIdx.x; i < BNODES; i += BLK) h[i] = 0;
    __syncthreads();
    const long stride = (long)gridDim.x * BLK;
    for (long e = (long)blockIdx.x * BLK + threadIdx.x; e < E; e += stride)
        atomicAdd(&h[col[e] >> BSHIFT], 1);
    __syncthreads();
    for (int i = threadIdx.x; i < BNODES; i += BLK)
        if (h[i]) atomicAdd(&bucketCnt[i], h[i]);
}

// single-block exclusive scan of bucketCnt[NB] -> bucketPtr, bucketCur.
__global__ void k_binscan(const int* __restrict__ bucketCnt, int* __restrict__ bucketPtr,
                          int* __restrict__ bucketCur, int NB, int E,
                          int* __restrict__ rowptrN) {
    __shared__ int lds[BLK];
    int t = threadIdx.x;
    int v0 = (2 * t < NB) ? bucketCnt[2 * t] : 0;
    int v1 = (2 * t + 1 < NB) ? bucketCnt[2 * t + 1] : 0;
    lds[t] = v0 + v1;
    __syncthreads();
    for (int off = 1; off < BLK; off <<= 1) {
        int mine = lds[t];
        int add = (t >= off) ? lds[t - off] : 0;
        __syncthreads();
        lds[t] = mine + add;
        __syncthreads();
    }
    int excl = (t > 0) ? lds[t - 1] : 0;
    if (2 * t < NB)     { bucketPtr[2 * t] = excl;          bucketCur[2 * t] = excl; }
    if (2 * t + 1 < NB) { bucketPtr[2 * t + 1] = excl + v0; bucketCur[2 * t + 1] = excl + v0; }
    if (t == 0) { bucketPtr[NB] = E; *rowptrN = E; }
}

// scatter (src,dst) pairs into bucket-grouped staging (CU-local write runs).
__global__ void k_binscatter(const int* __restrict__ row, const int* __restrict__ col,
                             int* __restrict__ bucketCur, int2* __restrict__ staging,
                             long E) {
    __shared__ int h[BNODES];
    __shared__ int gb[BNODES];
    __shared__ int lc[BNODES];
    const long e0 = (long)blockIdx.x * EB;
    const int n = (int)((E - e0 < EB) ? (E - e0) : EB);
    for (int i = threadIdx.x; i < BNODES; i += BLK) h[i] = 0;
    __syncthreads();
    for (int i = threadIdx.x; i < n; i += BLK)
        atomicAdd(&h[col[e0 + i] >> BSHIFT], 1);
    __syncthreads();
    for (int b = threadIdx.x; b < BNODES; b += BLK) {
        int c = h[b];
        gb[b] = c ? atomicAdd(&bucketCur[b], c) : 0;
        lc[b] = 0;
    }
    __syncthreads();
    for (int i = threadIdx.x; i < n; i += BLK) {
        int c = col[e0 + i];
        int r = row[e0 + i];
        int b = c >> BSHIFT;
        int pos = gb[b] + atomicAdd(&lc[b], 1);
        staging[pos] = make_int2(r, c);
    }
}

// one block per bucket: count/scan -> rowptr/dinv -> place src into CSR;
// fused: scale z0 rows of this bucket by dinv.
__global__ void k_bucket(const int2* __restrict__ staging, const int* __restrict__ bucketPtr,
                         int* __restrict__ edges, int* __restrict__ rowptr,
                         float* __restrict__ dinv, _Float16* __restrict__ z0, long N) {
    __shared__ int cnt[BNODES];
    __shared__ int cur[BNODES];
    __shared__ float dnv[BNODES];
    __shared__ int lds[BLK];
    const int b = blockIdx.x;
    const long lo = (long)b << BSHIFT;
    const int R = (int)(((N - lo) < BNODES) ? (N - lo) : BNODES);
    const int beg = bucketPtr[b];
    const int end = bucketPtr[b + 1];
    const int t = threadIdx.x;

    for (int i = t; i < BNODES; i += BLK) cnt[i] = 0;
    __syncthreads();
    for (int e = beg + t; e < end; e += BLK)
        atomicAdd(&cnt[staging[e].y - (int)lo], 1);
    __syncthreads();

    int v0 = cnt[2 * t];
    int v1 = cnt[2 * t + 1];
    lds[t] = v0 + v1;
    __syncthreads();
    for (int off = 1; off < BLK; off <<= 1) {
        int mine = lds[t];
        int add = (t >= off) ? lds[t - off] : 0;
        __syncthreads();
        lds[t] = mine + add;
        __syncthreads();
    }
    int excl = (t > 0) ? lds[t - 1] : 0;
    int e0 = beg + excl;
    int e1 = e0 + v0;
    cur[2 * t] = e0;
    cur[2 * t + 1] = e1;
    dnv[2 * t] = (v0 > 0) ? rsqrtf((float)v0) : 0.0f;
    dnv[2 * t + 1] = (v1 > 0) ? rsqrtf((float)v1) : 0.0f;
    if (2 * t < R)     { rowptr[lo + 2 * t] = e0;     dinv[lo + 2 * t] = dnv[2 * t]; }
    if (2 * t + 1 < R) { rowptr[lo + 2 * t + 1] = e1; dinv[lo + 2 * t + 1] = dnv[2 * t + 1]; }
    __syncthreads();

    for (int e = beg + t; e < end; e += BLK) {
        int2 p = staging[e];
        int pos = atomicAdd(&cur[p.y - (int)lo], 1);
        edges[pos] = p.x;
    }
    for (int i = t; i < R * 16; i += BLK) {
        int nloc = i >> 4;
        int q = i & 15;
        float d = dnv[nloc];
        h4* p = (h4*)(z0 + (lo + nloc) * DIMH) + q;
        *p = __builtin_convertvector(cvt(*p) * d, h4);
    }
}

// edge-sum core: 16 lanes per dst node, lane owns 4 dims (8B fp16 slice).
// Unrolled x8: mean degree 8 -> a typical node's full edge batch is ONE
// group of independent loads (halves the serialized latency chain vs x4).
__device__ inline f4 edge_sum(const _Float16* __restrict__ cur,
                              const int* __restrict__ edges,
                              int beg, int end, int q) {
    f4 s = {0.f, 0.f, 0.f, 0.f};
    f4 t2 = {0.f, 0.f, 0.f, 0.f};
    for (int base = beg; base < end; base += 16) {
        int me = base + q;
        int psrc = (me < end) ? edges[me] : 0;
        int n = end - base;
        if (n > 16) n = 16;
        int j = 0;
        for (; j + 8 <= n; j += 8) {
            int a0 = __shfl(psrc, j + 0, 16);
            int a1 = __shfl(psrc, j + 1, 16);
            int a2 = __shfl(psrc, j + 2, 16);
            int a3 = __shfl(psrc, j + 3, 16);
            int a4 = __shfl(psrc, j + 4, 16);
            int a5 = __shfl(psrc, j + 5, 16);
            int a6 = __shfl(psrc, j + 6, 16);
            int a7 = __shfl(psrc, j + 7, 16);
            h4 v0 = ((const h4*)(cur + (long)a0 * DIMH))[q];
            h4 v1 = ((const h4*)(cur + (long)a1 * DIMH))[q];
            h4 v2 = ((const h4*)(cur + (long)a2 * DIMH))[q];
            h4 v3 = ((const h4*)(cur + (long)a3 * DIMH))[q];
            h4 v4 = ((const h4*)(cur + (long)a4 * DIMH))[q];
            h4 v5 = ((const h4*)(cur + (long)a5 * DIMH))[q];
            h4 v6 = ((const h4*)(cur + (long)a6 * DIMH))[q];
            h4 v7 = ((const h4*)(cur + (long)a7 * DIMH))[q];
            s  += cvt(v0); t2 += cvt(v1); s  += cvt(v2); t2 += cvt(v3);
            s  += cvt(v4); t2 += cvt(v5); s  += cvt(v6); t2 += cvt(v7);
        }
        for (; j + 4 <= n; j += 4) {
            int a0 = __shfl(psrc, j + 0, 16);
            int a1 = __shfl(psrc, j + 1, 16);
            int a2 = __shfl(psrc, j + 2, 16);
            int a3 = __shfl(psrc, j + 3, 16);
            h4 v0 = ((const h4*)(cur + (long)a0 * DIMH))[q];
            h4 v1 = ((const h4*)(cur + (long)a1 * DIMH))[q];
            h4 v2 = ((const h4*)(cur + (long)a2 * DIMH))[q];
            h4 v3 = ((const h4*)(cur + (long)a3 * DIMH))[q];
            s  += cvt(v0); t2 += cvt(v1); s += cvt(v2); t2 += cvt(v3);
        }
        for (; j < n; ++j) {
            int a = __shfl(psrc, j, 16);
            s += cvt(((const h4*)(cur + (long)a * DIMH))[q]);
        }
    }
    return s + t2;
}

// layers 1..3: z_next = fp16(dinv^2 * sum z[src])
__global__ void __launch_bounds__(BLK)
k_gather(const _Float16* __restrict__ cur, _Float16* __restrict__ nxt,
         const float* __restrict__ dinv,
         const int* __restrict__ rowptr, const int* __restrict__ edges, long N) {
    long g = (long)blockIdx.x * BLK + threadIdx.x;
    if (g >= N * 16) return;
    long node = g >> 4;
    int q = (int)(g & 15);
    f4 s = edge_sum(cur, edges, rowptr[node], rowptr[node + 1], q);
    float d = dinv[node];
    ((h4*)(nxt + node * DIMH))[q] = __builtin_convertvector(s * (d * d), h4);
}

// layer 4 fused with final accumulate (algebra verified in r9 mega):
//   z4 = dinv^2 * sum z3[src]   (in-register)
//   acc = emb0/25 + (z1+z2+z3+z4) * sqrtdeg/25     (pure write)
__global__ void __launch_bounds__(BLK)
k_g4final(const float* __restrict__ uemb, const float* __restrict__ iemb,
          const _Float16* __restrict__ z1, const _Float16* __restrict__ z2,
          const _Float16* __restrict__ z3,
          const float* __restrict__ dinv,
          const int* __restrict__ rowptr, const int* __restrict__ edges,
          float* __restrict__ acc, long uElems, long N) {
    long g = (long)blockIdx.x * BLK + threadIdx.x;
    if (g >= N * 16) return;
    long node = g >> 4;
    int q = (int)(g & 15);
    f4 s = edge_sum(z3, edges, rowptr[node], rowptr[node + 1], q);
    float d = dinv[node];
    long off = node * DIMH + q * 4;
    f4 z4 = s * (d * d);
    f4 zs = cvt(*(const h4*)(z1 + off)) + cvt(*(const h4*)(z2 + off))
          + cvt(*(const h4*)(z3 + off)) + z4;
    float f = (d > 0.f) ? (1.0f / d) * (1.0f / 25.0f) : 0.f;
    f4 e0 = (off < uElems) ? *(const f4*)(uemb + off)
                           : *(const f4*)(iemb + (off - uElems));
    *(f4*)(acc + off) = e0 * (1.0f / 25.0f) + zs * f;
}

// ---------------------------------------------------------------------------
extern "C" void kernel_launch(void* const* d_in, const int* in_sizes, int n_in,
                              void* d_out, int out_size, void* d_ws, size_t ws_size,
                              hipStream_t stream) {
    const float* uemb = (const float*)d_in[0];
    const float* iemb = (const float*)d_in[1];
    const int*   edge = (const int*)d_in[2];

    const long uElems = in_sizes[0];          // 100000*64
    const long iElems = in_sizes[1];          // 50000*64
    const long E      = in_sizes[2] / 2;      // 1200000
    const long total  = uElems + iElems;      // N*64
    const long N      = total / DIMH;         // 150000

    const int* row = edge;      // edge_index[0] = src
    const int* col = edge + E;  // edge_index[1] = dst

    float* acc = (float*)d_out;
    const int NB = (int)((N + BNODES - 1) >> BSHIFT);   // 293 buckets

    // workspace layout (all bases 256B-aligned)
    const long Npad = (N + 63) & ~63L;
    const long Epad = (E + 63) & ~63L;
    int*      rowptr    = (int*)d_ws;                 // N+1 ints
    float*    dinv      = (float*)(rowptr + Npad + 64);
    int*      edges     = (int*)(dinv + Npad);        // E src indices
    int*      bucketCnt = edges + Epad;               // 1024
    int*      bucketPtr = bucketCnt + 1024;           // 1024 (NB+1 used)
    int*      bucketCur = bucketPtr + 1024;           // 1024
    _Float16* z0        = (_Float16*)(bucketCur + 1024); // N*64 fp16
    _Float16* z1        = z0 + total;
    _Float16* z2        = z1 + total;
    _Float16* z3        = z2 + total;
    int2*     staging   = (int2*)z1;   // E pairs; consumed by k_bucket before
                                       // gather-1 writes z1 (same stream)

    const long total4 = total / 4;
    const int gInit = (int)((total4 + BLK - 1) / BLK);
    k_init<<<gInit, BLK, 0, stream>>>(uemb, iemb, z0, bucketCnt, uElems, total);
    k_binhist<<<512, BLK, 0, stream>>>(col, bucketCnt, E);
    k_binscan<<<1, BLK, 0, stream>>>(bucketCnt, bucketPtr, bucketCur, NB, (int)E,
                                     rowptr + N);
    k_binscatter<<<(int)((E + EB - 1) / EB), BLK, 0, stream>>>(row, col, bucketCur,
                                                               staging, E);
    k_bucket<<<NB, BLK, 0, stream>>>(staging, bucketPtr, edges, rowptr, dinv, z0, N);

    const int gGather = (int)((N * 16 + BLK - 1) / BLK);
    k_gather<<<gGather, BLK, 0, stream>>>(z0, z1, dinv, rowptr, edges, N);
    k_gather<<<gGather, BLK, 0, stream>>>(z1, z2, dinv, rowptr, edges, N);
    k_gather<<<gGather, BLK, 0, stream>>>(z2, z3, dinv, rowptr, edges, N);
    k_g4final<<<gGather, BLK, 0, stream>>>(uemb, iemb, z1, z2, z3, dinv, rowptr,
                                           edges, acc, uElems, N);
}